// Round 1
// baseline (5898.153 us; speedup 1.0000x reference)
//
#include <hip/hip_runtime.h>
#include <hip/hip_bf16.h>
#include <math.h>

// ---------------- problem constants ----------------
#define BATCH 8
#define NCELLS 196          // 14*14
#define NCLS 20
#define HEADC 25            // 1 + 20 + 4

// ---------------- weight transpose: [co][ci][k] -> [ci][k][co] ----------------
template<int CIN, int COUT>
__global__ void transpose_w(const float* __restrict__ w, float* __restrict__ wt) {
    const int n = CIN * COUT * 9;
    for (int i = blockIdx.x * blockDim.x + threadIdx.x; i < n; i += gridDim.x * blockDim.x) {
        int k  = i % 9;
        int ci = (i / 9) % CIN;
        int co = i / (9 * CIN);
        wt[((size_t)ci * 9 + k) * COUT + co] = w[i];
    }
}

// ---------------- conv1: 3->64, 448->224, stride 2, SAME(pad_lo=0,pad_hi=1), ReLU ----------------
__global__ void conv1_kernel(const float* __restrict__ x, const float* __restrict__ w1,
                             float* __restrict__ out) {
    __shared__ float sW[27][64];
    for (int e = threadIdx.x; e < 1728; e += 256) {
        int k = e >> 6, co = e & 63;
        sW[k][co] = w1[co * 27 + k];
    }
    __syncthreads();
    int t = blockIdx.x * 256 + threadIdx.x;     // covers 8*8*224*224 exactly
    int ox  = t % 224;
    int rem = t / 224;
    int oy  = rem % 224;
    rem /= 224;
    int cog = rem & 7;
    int b   = rem >> 3;
    float acc[8] = {0.f,0.f,0.f,0.f,0.f,0.f,0.f,0.f};
    for (int ci = 0; ci < 3; ci++) {
        #pragma unroll
        for (int ky = 0; ky < 3; ky++) {
            int iy = 2 * oy + ky;
            if (iy >= 448) continue;
            #pragma unroll
            for (int kx = 0; kx < 3; kx++) {
                int ix = 2 * ox + kx;
                if (ix >= 448) continue;
                float iv = x[(((size_t)b * 3 + ci) * 448 + iy) * 448 + ix];
                int k = (ci * 3 + ky) * 3 + kx;
                float4 wa = *(const float4*)&sW[k][cog * 8];
                float4 wb = *(const float4*)&sW[k][cog * 8 + 4];
                acc[0] += wa.x * iv; acc[1] += wa.y * iv; acc[2] += wa.z * iv; acc[3] += wa.w * iv;
                acc[4] += wb.x * iv; acc[5] += wb.y * iv; acc[6] += wb.z * iv; acc[7] += wb.w * iv;
            }
        }
    }
    #pragma unroll
    for (int u = 0; u < 8; u++)
        out[(((size_t)b * 64 + cog * 8 + u) * 224 + oy) * 224 + ox] = fmaxf(acc[u], 0.f);
}

// ---------------- generic 3x3 stride-2 SAME conv, tiled ----------------
// Tile: 64 co x (16x16) px per block of 256 threads; thread = 8co x 8px.
// Input LDS rows padded to 64 floats with XOR-block swizzle (2-way banks = free, b128 aligned).
// wt is the transposed weight [ci][k][co].
// PARTIAL: store raw partial sums at out + ks*B*COUT*HOUT*WOUT (reduced+ReLU'd later);
// else store fmaxf(acc,0).
template<int CIN, int COUT, int HIN, int WIN, int KSPLIT, bool PARTIAL>
__launch_bounds__(256, 3)
__global__ void conv3x3s2(const float* __restrict__ in, const float* __restrict__ wt,
                          float* __restrict__ out) {
    constexpr int HOUT = HIN / 2, WOUT = WIN / 2;
    constexpr int NT   = (HOUT + 15) / 16;
    constexpr int COCH = COUT / 64;
    constexpr int KC   = 4;
    constexpr int CPS  = CIN / KSPLIT;          // channels per split
    constexpr size_t PSZ = (size_t)BATCH * COUT * HOUT * WOUT;

    __shared__ float sIn[KC][33][64];
    __shared__ float sW [KC][9][64];

    int bid = blockIdx.x;
    int ks  = bid % KSPLIT; bid /= KSPLIT;
    int tx  = bid % NT;     bid /= NT;
    int ty  = bid % NT;     bid /= NT;
    int cch = bid % COCH;
    int b   = bid / COCH;
    int cb  = cch * 64;

    const int tid  = threadIdx.x;
    const int cog  = tid >> 5;          // 0..7
    const int pxg  = tid & 31;          // 0..31
    const int row  = pxg >> 1;          // 0..15
    const int half = pxg & 1;           // 0..1

    float acc[8][8];
    #pragma unroll
    for (int u = 0; u < 8; u++)
        #pragma unroll
        for (int j = 0; j < 8; j++) acc[u][j] = 0.f;

    const int ci0 = ks * CPS;
    for (int cc = ci0; cc < ci0 + CPS; cc += KC) {
        __syncthreads();
        // ---- stage input tile: KC x 33 x 33 (swizzled store) ----
        for (int e = tid; e < KC * 33 * 33; e += 256) {
            int c   = e / 1089;
            int rem = e - c * 1089;
            int liy = rem / 33;
            int lix = rem - liy * 33;
            int iy  = ty * 32 + liy;
            int ix  = tx * 32 + lix;
            float v = 0.f;
            if (iy < HIN && ix < WIN)
                v = in[(((size_t)b * CIN + cc + c) * HIN + iy) * WIN + ix];
            int pl = (lix & 3) | ((((lix >> 2) ^ (liy & 15)) << 2));
            sIn[c][liy][pl] = v;
        }
        // ---- stage weights: KC x 9 x 64 (coalesced via transposed layout) ----
        for (int e = tid; e < KC * 9 * 64; e += 256) {
            int c   = e / 576;
            int rem = e - c * 576;
            int k   = rem >> 6;
            int co  = rem & 63;
            sW[c][k][co] = wt[((size_t)(cc + c) * 9 + k) * COUT + cb + co];
        }
        __syncthreads();
        // ---- compute ----
        #pragma unroll
        for (int c = 0; c < KC; c++) {
            #pragma unroll
            for (int ky = 0; ky < 3; ky++) {
                int liy = 2 * row + ky;
                int s   = liy & 15;
                float rin[20];
                #pragma unroll
                for (int m = 0; m < 5; m++) {
                    int pb = ((4 * half + m) ^ s) << 2;
                    float4 v = *(const float4*)&sIn[c][liy][pb];
                    rin[4 * m + 0] = v.x; rin[4 * m + 1] = v.y;
                    rin[4 * m + 2] = v.z; rin[4 * m + 3] = v.w;
                }
                #pragma unroll
                for (int kx = 0; kx < 3; kx++) {
                    const float* wp = &sW[c][ky * 3 + kx][cog * 8];
                    float wreg[8];
                    *(float4*)&wreg[0] = *(const float4*)wp;
                    *(float4*)&wreg[4] = *(const float4*)(wp + 4);
                    #pragma unroll
                    for (int jj = 0; jj < 8; jj++) {
                        float iv = rin[2 * jj + kx];
                        #pragma unroll
                        for (int u = 0; u < 8; u++) acc[u][jj] += wreg[u] * iv;
                    }
                }
            }
        }
    }
    // ---- store ----
    int oy = ty * 16 + row;
    int oxb = tx * 16 + half * 8;
    if (oy < HOUT) {
        #pragma unroll
        for (int u = 0; u < 8; u++) {
            size_t rowbase = (((size_t)b * COUT + cb + cog * 8 + u) * HOUT + oy) * WOUT;
            #pragma unroll
            for (int jj = 0; jj < 8; jj++) {
                int ox = oxb + jj;
                if (ox < WOUT) {
                    if (PARTIAL) out[(size_t)ks * PSZ + rowbase + ox] = acc[u][jj];
                    else         out[rowbase + ox] = fmaxf(acc[u][jj], 0.f);
                }
            }
        }
    }
}

// ---------------- deterministic K-split reductions (+ReLU) ----------------
__global__ void reduce2_relu(const float* __restrict__ p, float* __restrict__ o, int n) {
    int i = blockIdx.x * 256 + threadIdx.x;
    if (i < n) o[i] = fmaxf(p[i] + p[i + n], 0.f);
}
__global__ void reduce8_relu(const float* __restrict__ p, float* __restrict__ o, int n) {
    int i = blockIdx.x * 256 + threadIdx.x;
    if (i < n) {
        float s = 0.f;
        #pragma unroll
        for (int k = 0; k < 8; k++) s += p[(size_t)k * n + i];
        o[i] = fmaxf(s, 0.f);
    }
}

// ---------------- 1x1 head: wave per cell, lanes split ci ----------------
__global__ void head_kernel(const float* __restrict__ act, const float* __restrict__ wh,
                            float* __restrict__ pred) {
    int wave = threadIdx.x >> 6;
    int lane = threadIdx.x & 63;
    int cellid = blockIdx.x * 4 + wave;          // 0..1567
    int b = cellid / NCELLS, cell = cellid % NCELLS;
    float acc[HEADC];
    #pragma unroll
    for (int c = 0; c < HEADC; c++) acc[c] = 0.f;
    for (int it = 0; it < 8; it++) {
        int ci = it * 64 + lane;
        float a = act[((size_t)b * 512 + ci) * NCELLS + cell];
        #pragma unroll
        for (int c = 0; c < HEADC; c++) acc[c] += a * wh[c * 512 + ci];
    }
    #pragma unroll
    for (int c = 0; c < HEADC; c++) {
        float v = acc[c];
        v += __shfl_down(v, 32); v += __shfl_down(v, 16); v += __shfl_down(v, 8);
        v += __shfl_down(v, 4);  v += __shfl_down(v, 2);  v += __shfl_down(v, 1);
        if (lane == 0) pred[(size_t)cellid * HEADC + c] = v;
    }
}

// ---------------- decode: sigmoid/softmax/boxes ----------------
__global__ void decode_kernel(const float* __restrict__ pred, float* __restrict__ out,
                              float* __restrict__ cls) {
    int i = blockIdx.x * 256 + threadIdx.x;
    if (i >= BATCH * NCELLS) return;
    const float* p = pred + (size_t)i * HEADC;
    int cell = i % NCELLS;
    int gx = cell % 14, gy = cell / 14;
    float conf = 1.f / (1.f + expf(-p[0]));
    float m = p[1];
    #pragma unroll
    for (int c = 1; c < NCLS; c++) m = fmaxf(m, p[1 + c]);
    float e[NCLS], s = 0.f;
    #pragma unroll
    for (int c = 0; c < NCLS; c++) { e[c] = expf(p[1 + c] - m); s += e[c]; }
    float inv = conf / s;
    #pragma unroll
    for (int c = 0; c < NCLS; c++) cls[(size_t)i * NCLS + c] = e[c] * inv;
    float cx = (1.f / (1.f + expf(-p[21])) + gx) * 32.f;
    float cy = (1.f / (1.f + expf(-p[22])) + gy) * 32.f;
    float w  = expf(p[23]) * 32.f;
    float h  = expf(p[24]) * 32.f;
    float x1 = (cx - 0.5f * w) / 448.f, y1 = (cy - 0.5f * h) / 448.f;
    float x2 = (cx + 0.5f * w) / 448.f, y2 = (cy + 0.5f * h) / 448.f;
    x1 = fminf(fmaxf(x1, 0.f), 1.f); y1 = fminf(fmaxf(y1, 0.f), 1.f);
    x2 = fminf(fmaxf(x2, 0.f), 1.f); y2 = fminf(fmaxf(y2, 0.f), 1.f);
    float* o = out + (size_t)i * 24;
    o[0] = x1; o[1] = y1; o[2] = x2; o[3] = y2;
}

// ---------------- IoU matrices (per batch, 196x196) ----------------
__global__ void iou_kernel(const float* __restrict__ out, float* __restrict__ iou) {
    int idx = blockIdx.x * 256 + threadIdx.x;
    if (idx >= BATCH * NCELLS * NCELLS) return;
    int j = idx % NCELLS;
    int i = (idx / NCELLS) % NCELLS;
    int b = idx / (NCELLS * NCELLS);
    const float* bi = out + (((size_t)b * NCELLS) + i) * 24;
    const float* bj = out + (((size_t)b * NCELLS) + j) * 24;
    float ai = fmaxf(bi[2] - bi[0], 0.f) * fmaxf(bi[3] - bi[1], 0.f);
    float aj = fmaxf(bj[2] - bj[0], 0.f) * fmaxf(bj[3] - bj[1], 0.f);
    float ix1 = fmaxf(bi[0], bj[0]), iy1 = fmaxf(bi[1], bj[1]);
    float ix2 = fminf(bi[2], bj[2]), iy2 = fminf(bi[3], bj[3]);
    float inter = fmaxf(ix2 - ix1, 0.f) * fmaxf(iy2 - iy1, 0.f);
    iou[idx] = inter / (ai + aj - inter + 1e-14f);
}

// ---------------- per-(batch,class) greedy NMS + final score write ----------------
__global__ void nms_kernel(const float* __restrict__ cls, const float* __restrict__ iou,
                           float* __restrict__ out) {
    int b = blockIdx.x / NCLS;
    int c = blockIdx.x % NCLS;
    __shared__ float sc[NCELLS];
    __shared__ float ssort[NCELLS];
    __shared__ int   ord[NCELLS];
    __shared__ int   kp[NCELLS];
    int j = threadIdx.x;
    float sj = 0.f;
    if (j < NCELLS) {
        sj = cls[(((size_t)b * NCELLS) + j) * NCLS + c];
        sc[j] = sj;
    }
    __syncthreads();
    if (j < NCELLS) {
        int r = 0;
        for (int k = 0; k < NCELLS; k++) {
            float sk = sc[k];
            r += (sk > sj) || (sk == sj && k < j);   // stable descending rank
        }
        ord[r] = j; ssort[r] = sj; kp[r] = (sj > 0.01f) ? 1 : 0;
    }
    __syncthreads();
    int myo = (j < NCELLS) ? ord[j] : 0;
    const float* iob = iou + (size_t)b * NCELLS * NCELLS;
    for (int i = 0; i < NCELLS; i++) {
        __syncthreads();
        if (!kp[i]) continue;                        // uniform branch
        if (j > i && j < NCELLS && kp[j]) {
            if (iob[ord[i] * NCELLS + myo] > 0.5f) kp[j] = 0;
        }
    }
    __syncthreads();
    if (j < NCELLS)
        out[(((size_t)b * NCELLS) + ord[j]) * 24 + 4 + c] = kp[j] ? ssort[j] : 0.f;
}

// ---------------- launch ----------------
extern "C" void kernel_launch(void* const* d_in, const int* in_sizes, int n_in,
                              void* d_out, int out_size, void* d_ws, size_t ws_size,
                              hipStream_t stream) {
    const float* x  = (const float*)d_in[0];
    const float* w1 = (const float*)d_in[1];
    const float* w2 = (const float*)d_in[2];
    const float* w3 = (const float*)d_in[3];
    const float* w4 = (const float*)d_in[4];
    const float* w5 = (const float*)d_in[5];
    const float* wh = (const float*)d_in[6];
    float* out = (float*)d_out;
    float* ws  = (float*)d_ws;

    // workspace layout (floats)
    float* A     = ws;                         // 25,690,112 (conv1 out; later part5/act5/pred/cls/iou)
    float* Bp    = ws + 25690112;              // 12,845,056 (conv2 out; later part4/act3)
    float* part4 = Bp;                         // 2 x 3,211,264 = 6,422,528
    float* act3  = Bp + 6422528;               // 3,211,264
    float* part5 = A;                          // 8 x 802,816 = 6,422,528
    float* act5  = A + 6422528;                // 802,816
    float* pred  = A + 7225344;                // 39,200
    float* clsb  = A + 7264544;                // 31,360
    float* ioub  = A + 7295904;                // 307,328
    float* WT    = ws + 38535168;              // transposed weights, 3,907,584 total
    float* wt2 = WT;
    float* wt3 = WT + 73728;
    float* wt4 = WT + 368640;
    float* wt5 = WT + 1548288;

    transpose_w<64, 128><<<256,  256, 0, stream>>>(w2, wt2);
    transpose_w<128, 256><<<512, 256, 0, stream>>>(w3, wt3);
    transpose_w<256, 512><<<1024,256, 0, stream>>>(w4, wt4);
    transpose_w<512, 512><<<2048,256, 0, stream>>>(w5, wt5);

    conv1_kernel<<<12544, 256, 0, stream>>>(x, w1, A);

    // conv2: 64->128, 224->112 : grid = 8 * 2 * 7*7 = 784
    conv3x3s2<64, 128, 224, 224, 1, false><<<784, 256, 0, stream>>>(A, wt2, Bp);
    // conv3: 128->256, 112->56 : grid = 8 * 4 * 4*4 = 512
    conv3x3s2<128, 256, 112, 112, 1, false><<<512, 256, 0, stream>>>(Bp, wt3, A);
    // conv4: 256->512, 56->28, KSPLIT=2 : grid = 8 * 8 * 2*2 * 2 = 512
    conv3x3s2<256, 512, 56, 56, 2, true><<<512, 256, 0, stream>>>(A, wt4, part4);
    reduce2_relu<<<12544, 256, 0, stream>>>(part4, act3, 3211264);
    // conv5: 512->512, 28->14, KSPLIT=8 : grid = 8 * 8 * 1 * 8 = 512
    conv3x3s2<512, 512, 28, 28, 8, true><<<512, 256, 0, stream>>>(act3, wt5, part5);
    reduce8_relu<<<3136, 256, 0, stream>>>(part5, act5, 802816);

    head_kernel<<<392, 256, 0, stream>>>(act5, wh, pred);
    decode_kernel<<<7, 256, 0, stream>>>(pred, out, clsb);
    iou_kernel<<<1201, 256, 0, stream>>>(out, ioub);
    nms_kernel<<<160, 256, 0, stream>>>(clsb, ioub, out);
}